// Round 8
// baseline (31165.384 us; speedup 1.0000x reference)
//
#include <hip/hip_runtime.h>
#include <stdint.h>

// ---------------- constants ----------------
#define T_STEPS 1000
#define BATCHN  4096
#define SDIM    128
#define ADIM    32
#define HID     256
#define TDIM    16
#define KPH32   260   // u32 stride for hidden activation rows (256 used + 4 pad)
#define KPX32   36    // u32 stride for x rows (32 used + 4 pad); 36*4=144 B, 16-aligned

typedef __attribute__((ext_vector_type(8))) short short8;     // 8 bf16 (4 VGPRs)
typedef __attribute__((ext_vector_type(4))) float f32x4;      // MFMA accumulator
typedef __attribute__((ext_vector_type(4))) unsigned int u32x4;

union BPack { short8 s8; uint32_t u[4]; };

// ---------------- bf16 helpers ----------------
__device__ __forceinline__ unsigned short f2bf(float f) {   // RNE
  uint32_t u = __float_as_uint(f);
  u = u + 0x7FFFu + ((u >> 16) & 1u);
  return (unsigned short)(u >> 16);
}
__device__ __forceinline__ float bf2f(unsigned short h) {
  return __uint_as_float(((uint32_t)h) << 16);
}
// activation element: low16 = hi-bf16(RNE), high16 = lo-bf16 of residual
__device__ __forceinline__ uint32_t pack2(float v) {
  unsigned short h = f2bf(v);
  unsigned short l = f2bf(v - bf2f(h));
  return (uint32_t)h | ((uint32_t)l << 16);
}
// deinterleave 8 packed u32 (16B-aligned) into hi/lo short8 fragments
__device__ __forceinline__ void deint(const uint32_t* __restrict__ p, short8& ah, short8& al) {
  u32x4 a = *reinterpret_cast<const u32x4*>(p);
  u32x4 b = *reinterpret_cast<const u32x4*>(p + 4);
  BPack H, L;
  uint32_t u[8] = {a.x, a.y, a.z, a.w, b.x, b.y, b.z, b.w};
#pragma unroll
  for (int q = 0; q < 4; ++q) {
    uint32_t u0 = u[2 * q], u1 = u[2 * q + 1];
    H.u[q] = (u0 & 0xFFFFu) | (u1 << 16);
    L.u[q] = (u0 >> 16) | (u1 & 0xFFFF0000u);
  }
  ah = H.s8; al = L.s8;
}
// split f32 weights into (hi RTZ-bf16, lo RTZ-bf16 of exact residual) — same as R7
__device__ __forceinline__ void pack_split(const uint32_t u[8], short8& h, short8& l) {
  BPack hh, ll;
#pragma unroll
  for (int q = 0; q < 4; ++q) {
    uint32_t u0 = u[2 * q], u1 = u[2 * q + 1];
    hh.u[q] = (u0 >> 16) | (u1 & 0xFFFF0000u);
    float f0 = __uint_as_float(u0) - __uint_as_float(u0 & 0xFFFF0000u);  // exact
    float f1 = __uint_as_float(u1) - __uint_as_float(u1 & 0xFFFF0000u);  // exact
    ll.u[q] = (__float_as_uint(f0) >> 16) | (__float_as_uint(f1) & 0xFFFF0000u);
  }
  h = hh.s8; l = ll.s8;
}

// ---------------- threefry2x32 (exact JAX semantics) ----------------
__device__ __forceinline__ uint32_t rotl32(uint32_t v, int d) {
  return (v << d) | (v >> (32 - d));
}
__device__ __forceinline__ void threefry2x32(uint32_t k0, uint32_t k1,
                                             uint32_t x0, uint32_t x1,
                                             uint32_t& o0, uint32_t& o1) {
  uint32_t ks0 = k0, ks1 = k1, ks2 = k0 ^ k1 ^ 0x1BD11BDAu;
  x0 += ks0; x1 += ks1;
#define TF_ROUND(r) { x0 += x1; x1 = rotl32(x1, (r)); x1 ^= x0; }
  TF_ROUND(13) TF_ROUND(15) TF_ROUND(26) TF_ROUND(6)
  x0 += ks1; x1 += ks2 + 1u;
  TF_ROUND(17) TF_ROUND(29) TF_ROUND(16) TF_ROUND(24)
  x0 += ks2; x1 += ks0 + 2u;
  TF_ROUND(13) TF_ROUND(15) TF_ROUND(26) TF_ROUND(6)
  x0 += ks0; x1 += ks1 + 3u;
  TF_ROUND(17) TF_ROUND(29) TF_ROUND(16) TF_ROUND(24)
  x0 += ks1; x1 += ks2 + 4u;
  TF_ROUND(13) TF_ROUND(15) TF_ROUND(26) TF_ROUND(6)
  x0 += ks2; x1 += ks0 + 5u;
#undef TF_ROUND
  o0 = x0; o1 = x1;
}
// JAX partitionable threefry random_bits (bit_width=32): XOR combine of both words.
__device__ __forceinline__ uint32_t random_bits32_partitionable(uint32_t k0, uint32_t k1,
                                                               uint32_t j) {
  uint32_t o0, o1;
  threefry2x32(k0, k1, 0u, j, o0, o1);
  return o0 ^ o1;
}

// ---------------- XLA ErfInv (f32 Giles polynomial) ----------------
__device__ __forceinline__ float erfinv_f32(float x) {
  float w = -log1pf(-(x * x));
  float p;
  if (w < 5.0f) {
    w = w - 2.5f;
    p = 2.81022636e-08f;
    p = fmaf(p, w, 3.43273939e-07f);
    p = fmaf(p, w, -3.5233877e-06f);
    p = fmaf(p, w, -4.39150654e-06f);
    p = fmaf(p, w, 0.00021858087f);
    p = fmaf(p, w, -0.00125372503f);
    p = fmaf(p, w, -0.00417768164f);
    p = fmaf(p, w, 0.246640727f);
    p = fmaf(p, w, 1.50140941f);
  } else {
    w = sqrtf(w) - 3.0f;
    p = -0.000200214257f;
    p = fmaf(p, w, 0.000100950558f);
    p = fmaf(p, w, 0.00134934322f);
    p = fmaf(p, w, -0.00367342844f);
    p = fmaf(p, w, 0.00573950773f);
    p = fmaf(p, w, -0.0076224613f);
    p = fmaf(p, w, 0.00943887047f);
    p = fmaf(p, w, 1.00167406f);
    p = fmaf(p, w, 2.83297682f);
  }
  return p * x;
}
__device__ __forceinline__ float bits_to_normal(uint32_t bits) {
  float f = __uint_as_float((bits >> 9) | 0x3F800000u) - 1.0f;   // [0,1)
  float u = f * 2.0f + (-0.99999994f);
  u = fmaxf(-0.99999994f, u);
  return 1.41421356237309515f * erfinv_f32(u);   // sqrt(2) as f32
}

// mish(x) = x * t/(t+2), t = e^x (e^x + 2); clamp arg (identical in f32 for x>=20)
__device__ __forceinline__ float mish_f(float x) {
  float e = expf(fminf(x, 20.0f));
  float t = fmaf(e, e, 2.0f * e);
  return x * (t / (t + 2.0f));
}

// ---------------- precompute: tf_all[1000][16], coefs[5][1000], keys[1000][2] --------
__global__ __launch_bounds__(64)
void precompute_kernel(const float* __restrict__ w_t1, const float* __restrict__ b_t1,
                       const float* __restrict__ w_t2, const float* __restrict__ b_t2,
                       float* __restrict__ tf_all, float* __restrict__ coefs,
                       uint32_t* __restrict__ keys) {
  const int i = blockIdx.x;
  const int j = threadIdx.x;
  const float tv = (float)i;
  __shared__ float hid[32];
  const float CF = (float)(-1.3157629102823120);  // -log(10000)/7
  if (j < 32) {
    float acc = b_t1[j];
#pragma unroll
    for (int k = 0; k < 16; ++k) {
      int kf = (k < 8) ? k : (k - 8);
      float fr = expf((float)kf * CF);
      float ang = tv * fr;
      float te = (k < 8) ? sinf(ang) : cosf(ang);
      acc = fmaf(te, w_t1[k * 32 + j], acc);
    }
    hid[j] = mish_f(acc);
  }
  __syncthreads();
  if (j < 16) {
    float acc = b_t2[j];
#pragma unroll
    for (int k2 = 0; k2 < 32; ++k2) acc = fmaf(hid[k2], w_t2[k2 * 16 + j], acc);
    tf_all[i * TDIM + j] = acc;
  }
  if (j == 0) {
    double t = (double)(i + 1);
    double ac  = exp(-0.1 * t / 1000.0 - 4.95 * t * t / 1.0e6);
    double acp = (i == 0) ? 1.0
        : exp(-0.1 * (t - 1.0) / 1000.0 - 4.95 * (t - 1.0) * (t - 1.0) / 1.0e6);
    double alpha = exp(-0.1 / 1000.0 - 4.95 * (2.0 * t - 1.0) / 1.0e6);
    double beta = 1.0 - alpha;
    double sr   = sqrt(1.0 / ac);
    double srm1 = sqrt(1.0 / ac - 1.0);
    double c1 = beta * sqrt(acp) / (1.0 - ac);
    double c2 = (1.0 - acp) * sqrt(alpha) / (1.0 - ac);
    double pv = beta * (1.0 - acp) / (1.0 - ac);
    double lv = log(fmax(pv, 1.0e-20));
    coefs[0 * T_STEPS + i] = (float)sr;
    coefs[1 * T_STEPS + i] = (float)srm1;
    coefs[2 * T_STEPS + i] = (float)c1;
    coefs[3 * T_STEPS + i] = (float)c2;
    float lvf = (float)lv;
    coefs[4 * T_STEPS + i] = expf(0.5f * lvf);
    uint32_t o0, o1;
    threefry2x32(0u, 1u, 0u, (uint32_t)i, o0, o1);
    keys[2 * i]     = o0;
    keys[2 * i + 1] = o1;
  }
}

// ------- tfc[t][n] = b0[n] + sum_k tf[t][k] * w0[(32+k)*256+n]  (fp32) -------------
__global__ __launch_bounds__(256)
void tfc_kernel(const float* __restrict__ tf_all, const float* __restrict__ w0,
                const float* __restrict__ b0, float* __restrict__ tfc) {
  const int t = blockIdx.x, n = threadIdx.x;
  __shared__ float tf[TDIM];
  if (n < TDIM) tf[n] = tf_all[t * TDIM + n];
  __syncthreads();
  float acc = b0[n];
#pragma unroll
  for (int k = 0; k < TDIM; ++k) acc = fmaf(tf[k], w0[(ADIM + k) * HID + n], acc);
  tfc[t * HID + n] = acc;
}

// ------- dense layer: split-bf16 MFMA, 4 row-tiles per wave, weights f32 from d_in --
// MODE 0: L0 (adds sc+tfc, mish). MODE 1: hidden (bias+mish).
template <int NKT, int MODE>
__device__ __forceinline__ void dense_g4(
    const float* __restrict__ W, int N,
    const uint32_t* __restrict__ src, int sstride,
    uint32_t* __restrict__ dst, int dstride,
    float bA, float bB,
    const float* __restrict__ sc0, const float* __restrict__ sc1,  // [16] regs or null
    float tf0, float tf1,
    int lrow, int quad, int nt0, int nt1) {
  f32x4 acc0[4], acc1[4];
#pragma unroll
  for (int g = 0; g < 4; ++g) {
    acc0[g] = {0.f, 0.f, 0.f, 0.f};
    acc1[g] = {0.f, 0.f, 0.f, 0.f};
  }
  const int n0 = nt0 * 16 + lrow, n1 = nt1 * 16 + lrow;
  uint32_t cu0[8], cu1[8], nu0[8], nu1[8];
  const float* p0 = W + quad * 8 * N + n0;
  const float* p1 = W + quad * 8 * N + n1;
#pragma unroll
  for (int j = 0; j < 8; ++j) {
    cu0[j] = __float_as_uint(p0[j * N]);
    cu1[j] = __float_as_uint(p1[j * N]);
  }
  for (int kt = 0; kt < NKT; ++kt) {
    if (kt + 1 < NKT) {
      const float* q0 = p0 + (kt + 1) * 32 * N;
      const float* q1 = p1 + (kt + 1) * 32 * N;
#pragma unroll
      for (int j = 0; j < 8; ++j) {
        nu0[j] = __float_as_uint(q0[j * N]);
        nu1[j] = __float_as_uint(q1[j * N]);
      }
    }
    short8 bh0, bl0, bh1, bl1;
    pack_split(cu0, bh0, bl0);
    pack_split(cu1, bh1, bl1);
#pragma unroll
    for (int g = 0; g < 4; ++g) {
      const uint32_t* ap = src + (16 * g + lrow) * sstride + kt * 32 + quad * 8;
      short8 ah, al;
      deint(ap, ah, al);
      acc0[g] = __builtin_amdgcn_mfma_f32_16x16x32_bf16(ah, bh0, acc0[g], 0, 0, 0);
      acc1[g] = __builtin_amdgcn_mfma_f32_16x16x32_bf16(ah, bh1, acc1[g], 0, 0, 0);
      acc0[g] = __builtin_amdgcn_mfma_f32_16x16x32_bf16(al, bh0, acc0[g], 0, 0, 0);
      acc1[g] = __builtin_amdgcn_mfma_f32_16x16x32_bf16(al, bh1, acc1[g], 0, 0, 0);
      acc0[g] = __builtin_amdgcn_mfma_f32_16x16x32_bf16(ah, bl0, acc0[g], 0, 0, 0);
      acc1[g] = __builtin_amdgcn_mfma_f32_16x16x32_bf16(ah, bl1, acc1[g], 0, 0, 0);
    }
#pragma unroll
    for (int j = 0; j < 8; ++j) { cu0[j] = nu0[j]; cu1[j] = nu1[j]; }
  }
  // epilogue: C/D layout col = lane&15, row = quad*4 + reg (row-tile offset 16g)
#pragma unroll
  for (int g = 0; g < 4; ++g) {
#pragma unroll
    for (int reg = 0; reg < 4; ++reg) {
      int orow = 16 * g + quad * 4 + reg;
      float v0, v1;
      if (MODE == 0) {
        v0 = mish_f(acc0[g][reg] + sc0[g * 4 + reg] + tf0);
        v1 = mish_f(acc1[g][reg] + sc1[g * 4 + reg] + tf1);
      } else {
        v0 = mish_f(acc0[g][reg] + bA);
        v1 = mish_f(acc1[g][reg] + bB);
      }
      dst[orow * dstride + n0] = pack2(v0);
      dst[orow * dstride + n1] = pack2(v1);  // n1-n0=64B: fusable ds_write2_b32
    }
  }
}

// ------- final layer 256->32: waves 0,1 (tile = w), 4 row-tiles ----------------------
__device__ __forceinline__ void final_g4(
    const float* __restrict__ wf, const uint32_t* __restrict__ src,
    float bfv, float* __restrict__ eps, int lrow, int quad, int tile) {
  f32x4 acc[4];
#pragma unroll
  for (int g = 0; g < 4; ++g) acc[g] = {0.f, 0.f, 0.f, 0.f};
  uint32_t cu[8], nu[8];
  const float* p = wf + quad * 8 * ADIM + tile * 16 + lrow;
#pragma unroll
  for (int j = 0; j < 8; ++j) cu[j] = __float_as_uint(p[j * ADIM]);
  for (int kt = 0; kt < 8; ++kt) {
    if (kt + 1 < 8) {
      const float* q = p + (kt + 1) * 32 * ADIM;
#pragma unroll
      for (int j = 0; j < 8; ++j) nu[j] = __float_as_uint(q[j * ADIM]);
    }
    short8 bh, bl;
    pack_split(cu, bh, bl);
#pragma unroll
    for (int g = 0; g < 4; ++g) {
      const uint32_t* ap = src + (16 * g + lrow) * KPH32 + kt * 32 + quad * 8;
      short8 ah, al;
      deint(ap, ah, al);
      acc[g] = __builtin_amdgcn_mfma_f32_16x16x32_bf16(ah, bh, acc[g], 0, 0, 0);
      acc[g] = __builtin_amdgcn_mfma_f32_16x16x32_bf16(al, bh, acc[g], 0, 0, 0);
      acc[g] = __builtin_amdgcn_mfma_f32_16x16x32_bf16(ah, bl, acc[g], 0, 0, 0);
    }
#pragma unroll
    for (int j = 0; j < 8; ++j) cu[j] = nu[j];
  }
#pragma unroll
  for (int g = 0; g < 4; ++g)
#pragma unroll
    for (int reg = 0; reg < 4; ++reg)
      eps[(16 * g + quad * 4 + reg) * ADIM + tile * 16 + lrow] = acc[g][reg] + bfv;
}

// ---------------- persistent main kernel: 64 blocks x 64 rows ---------------------
__global__ __launch_bounds__(512)
void diffusion_main(const float* __restrict__ state, const float* __restrict__ x_init,
                    const float* __restrict__ w0, const float* __restrict__ b1,
                    const float* __restrict__ b2, const float* __restrict__ bf,
                    const float* __restrict__ w1, const float* __restrict__ w2,
                    const float* __restrict__ wf,
                    const float* __restrict__ tfc, const float* __restrict__ coefs,
                    const uint32_t* __restrict__ keys, float* __restrict__ out) {
  // LDS: 2*66560 + 9216 + 2*8192 = 158720 B
  __shared__ __align__(16) uint32_t QA[64 * KPH32];
  __shared__ __align__(16) uint32_t PA[64 * KPH32];
  __shared__ __align__(16) uint32_t A0A[64 * KPX32];
  __shared__ float s_x[64 * ADIM];
  __shared__ float s_eps[64 * ADIM];

  const int tid = threadIdx.x;          // 0..511
  const int base = blockIdx.x * 64;     // 64 rows per block
  const int l = tid & 63;
  const int w = tid >> 6;               // wave 0..7
  const int lrow = l & 15;
  const int quad = l >> 4;
  const int nt0 = 2 * w, nt1 = 2 * w + 1;
  const int n0 = nt0 * 16 + lrow, n1 = nt1 * 16 + lrow;

  // ---- init x ----
  for (int idx = tid; idx < 64 * ADIM; idx += 512) {
    int r = idx >> 5, d = idx & 31;
    float v = x_init[(base + r) * ADIM + d];
    s_x[r * ADIM + d] = v;
    A0A[r * KPX32 + d] = pack2(v);
  }
  // ---- stage state f32 (transient overlay on QA), compute sc in registers --------
  float* stateF = reinterpret_cast<float*>(QA);   // 64*128*4 = 32768 B <= QA
  for (int idx = tid; idx < 64 * SDIM; idx += 512) {
    int r = idx >> 7, k = idx & 127;
    stateF[r * SDIM + k] = state[(base + r) * SDIM + k];
  }
  __syncthreads();
  float sc0[16], sc1[16];
#pragma unroll
  for (int i = 0; i < 16; ++i) { sc0[i] = 0.0f; sc1[i] = 0.0f; }
  for (int kc = 0; kc < 8; ++kc) {
    float wA[16], wB[16];
#pragma unroll
    for (int j = 0; j < 16; ++j) {
      wA[j] = w0[(ADIM + TDIM + kc * 16 + j) * HID + n0];
      wB[j] = w0[(ADIM + TDIM + kc * 16 + j) * HID + n1];
    }
#pragma unroll
    for (int g = 0; g < 4; ++g) {
#pragma unroll
      for (int reg = 0; reg < 4; ++reg) {
        int row = 16 * g + quad * 4 + reg;
        const float* sp = stateF + row * SDIM + kc * 16;
        float a0 = sc0[g * 4 + reg], a1 = sc1[g * 4 + reg];
#pragma unroll
        for (int q = 0; q < 4; ++q) {
          float4 s4 = *reinterpret_cast<const float4*>(sp + q * 4);
          a0 = fmaf(s4.x, wA[q * 4 + 0], a0); a1 = fmaf(s4.x, wB[q * 4 + 0], a1);
          a0 = fmaf(s4.y, wA[q * 4 + 1], a0); a1 = fmaf(s4.y, wB[q * 4 + 1], a1);
          a0 = fmaf(s4.z, wA[q * 4 + 2], a0); a1 = fmaf(s4.z, wB[q * 4 + 2], a1);
          a0 = fmaf(s4.w, wA[q * 4 + 3], a0); a1 = fmaf(s4.w, wB[q * 4 + 3], a1);
        }
        sc0[g * 4 + reg] = a0; sc1[g * 4 + reg] = a1;
      }
    }
  }
  __syncthreads();   // done reading stateF before QA is reused by L0

  const float b1A = b1[n0], b1B = b1[n1];
  const float b2A = b2[n0], b2B = b2[n1];
  const float bfv = (w < 2) ? bf[w * 16 + lrow] : 0.0f;

  for (int t = T_STEPS - 1; t >= 0; --t) {
    float tf0 = tfc[t * HID + n0];
    float tf1 = tfc[t * HID + n1];
    __syncthreads();   // posterior A0A/s_x writes visible
    // L0: A0 (K=32) -> QA
    dense_g4<1, 0>(w0, HID, A0A, KPX32, QA, KPH32, 0.f, 0.f,
                   sc0, sc1, tf0, tf1, lrow, quad, nt0, nt1);
    __syncthreads();
    // L1: QA -> PA
    dense_g4<8, 1>(w1, HID, QA, KPH32, PA, KPH32, b1A, b1B,
                   nullptr, nullptr, 0.f, 0.f, lrow, quad, nt0, nt1);
    __syncthreads();
    // L2: PA -> QA
    dense_g4<8, 1>(w2, HID, PA, KPH32, QA, KPH32, b2A, b2B,
                   nullptr, nullptr, 0.f, 0.f, lrow, quad, nt0, nt1);
    __syncthreads();
    // Lf: QA -> eps (waves 0,1; tile = w)
    if (w < 2) final_g4(wf, QA, bfv, s_eps, lrow, quad, w);
    __syncthreads();
    // posterior + JAX noise; 4 rows per thread
#pragma unroll
    for (int i = 0; i < 4; ++i) {
      int r = (tid >> 5) + 16 * i;
      int d = tid & 31;
      float sr  = coefs[0 * T_STEPS + t];
      float srm = coefs[1 * T_STEPS + t];
      float c1  = coefs[2 * T_STEPS + t];
      float c2  = coefs[3 * T_STEPS + t];
      float sig = (t != 0) ? coefs[4 * T_STEPS + t] : 0.0f;
      uint32_t k0 = keys[2 * t], k1 = keys[2 * t + 1];
      uint32_t jflat = (uint32_t)((base + r) * ADIM + d);
      float nz = bits_to_normal(random_bits32_partitionable(k0, k1, jflat));
      float xv = s_x[r * ADIM + d];
      float ev = s_eps[r * ADIM + d];
      float x0v = fminf(fmaxf(sr * xv - srm * ev, -1.0f), 1.0f);
      float xn = c1 * x0v + c2 * xv + sig * nz;
      s_x[r * ADIM + d] = xn;
      A0A[r * KPX32 + d] = pack2(xn);
    }
    // next-iter leading barrier orders these writes before L0 reads.
  }
  __syncthreads();
  for (int idx = tid; idx < 64 * ADIM; idx += 512) {
    int r = idx >> 5, d = idx & 31;
    out[(base + r) * ADIM + d] = fminf(fmaxf(s_x[r * ADIM + d], -1.0f), 1.0f);
  }
}

// ---------------- launcher ----------------
extern "C" void kernel_launch(void* const* d_in, const int* in_sizes, int n_in,
                              void* d_out, int out_size, void* d_ws, size_t ws_size,
                              hipStream_t stream) {
  const float* state = (const float*)d_in[0];
  const float* x_init = (const float*)d_in[1];
  const float* w_t1 = (const float*)d_in[2];
  const float* b_t1 = (const float*)d_in[3];
  const float* w_t2 = (const float*)d_in[4];
  const float* b_t2 = (const float*)d_in[5];
  const float* w0 = (const float*)d_in[6];
  const float* b0 = (const float*)d_in[7];
  const float* w1 = (const float*)d_in[8];
  const float* b1 = (const float*)d_in[9];
  const float* w2 = (const float*)d_in[10];
  const float* b2 = (const float*)d_in[11];
  const float* wf = (const float*)d_in[12];
  const float* bf = (const float*)d_in[13];
  float* out = (float*)d_out;

  // ws layout: tf_all[16000] f32 | coefs[5000] f32 | keys[2000] u32 | tfc[256000] f32
  float* tf_all = (float*)d_ws;
  float* coefs = tf_all + T_STEPS * TDIM;
  uint32_t* keys = (uint32_t*)(coefs + 5 * T_STEPS);
  float* tfc = (float*)(keys + 2 * T_STEPS);

  precompute_kernel<<<T_STEPS, 64, 0, stream>>>(w_t1, b_t1, w_t2, b_t2, tf_all, coefs, keys);
  tfc_kernel<<<T_STEPS, 256, 0, stream>>>(tf_all, w0, b0, tfc);
  diffusion_main<<<64, 512, 0, stream>>>(state, x_init, w0, b1, b2, bf, w1, w2, wf,
                                         tfc, coefs, keys, out);
}